// Round 1
// baseline (483.442 us; speedup 1.0000x reference)
//
#include <hip/hip_runtime.h>

// Capsule dynamic routing, fused-recompute strategy.
// u_i: (B,N,DI) f32, weight: (1,N,NO,DI,DE) f32, bias: (N,NO,1) f32, r=3.
// u_ji[b,n,o,e] = sum_d u_i[b,n,d]*w[n,o,d,e] + bias[n,o]  -- NEVER materialized.
// Pipeline per call: memset(logits=0); 3x{phase1 -> squash}; phase2 after iters 0,1.

#define B    256
#define N    1152
#define NO   10
#define DI   8
#define DE   16
#define NT   16      // n tiles  (N/NT = 72 n per block)
#define NPB  72
#define BT   16      // b tiles  (B/BT = 16 b per block)
#define BPB  16
#define THREADS 512

// ws layout in floats
#define LOGITS_OFF 0
#define LOGITS_SZ  (B * N * NO)                  // 2,949,120
#define SPART_OFF  (LOGITS_OFF + LOGITS_SZ)
#define SPART_SZ   (NT * B * NO * DE)            // 655,360
#define V_OFF      (SPART_OFF + SPART_SZ)
#define V_SZ       (B * NO * DE)                 // 40,960
#define SV_OFF     (V_OFF + V_SZ)
#define SV_SZ      (B * NO)                      // 2,560

// ---------------------------------------------------------------------------
// Phase 1: c = softmax(logits, axis=o); s_part[nt][b][o][e] = sum_{n in tile} c*u_ji
// Thread map: tid = bb(4b)<<5 | npar(3b)<<2 | e4(2b).
//   bb   : which of 16 batch elems in this block's b-tile
//   e4   : which aligned group of 4 e's (float4 over e)
//   npar : 8-way split of the n loop, reduced by shfl_xor(4,8,16) at the end
// ---------------------------------------------------------------------------
__global__ __launch_bounds__(THREADS)
void phase1_kernel(const float* __restrict__ u,
                   const float* __restrict__ w,
                   const float* __restrict__ bias,
                   const float* __restrict__ logits,
                   float* __restrict__ s_part) {
    __shared__ float c_s[BPB * NPB * NO];   // 46,080 B
    const int n0 = blockIdx.x * NPB;
    const int b0 = blockIdx.y * BPB;
    const int tid = threadIdx.x;

    // --- softmax over o for each (bb, nn) row, into LDS ---
    for (int rIdx = tid; rIdx < BPB * NPB; rIdx += THREADS) {
        const int bb = rIdx / NPB;
        const int nn = rIdx % NPB;
        const float* lrow = logits + ((size_t)(b0 + bb) * N + (n0 + nn)) * NO;
        float x[NO];
        float m = -1e30f;
#pragma unroll
        for (int o = 0; o < NO; ++o) { x[o] = lrow[o]; m = fmaxf(m, x[o]); }
        float sum = 0.f;
#pragma unroll
        for (int o = 0; o < NO; ++o) { x[o] = __expf(x[o] - m); sum += x[o]; }
        const float inv = 1.f / sum;
#pragma unroll
        for (int o = 0; o < NO; ++o) c_s[rIdx * NO + o] = x[o] * inv;
    }
    __syncthreads();

    const int bb   = tid >> 5;
    const int sub  = tid & 31;
    const int npar = sub >> 2;
    const int e4   = sub & 3;
    const int b    = b0 + bb;

    float4 acc[NO];
#pragma unroll
    for (int o = 0; o < NO; ++o) acc[o] = make_float4(0.f, 0.f, 0.f, 0.f);

    for (int nl = npar; nl < NPB; nl += 8) {
        const int n = n0 + nl;
        const float* up = u + ((size_t)b * N + n) * DI;
        const float4 u0 = *(const float4*)up;
        const float4 u1 = *(const float4*)(up + 4);
        const float ur[DI] = {u0.x, u0.y, u0.z, u0.w, u1.x, u1.y, u1.z, u1.w};
        const float* wp = w + (size_t)n * (NO * DI * DE) + e4 * 4;
        const float* bp = bias + n * NO;
        const float* cp = c_s + (bb * NPB + nl) * NO;
#pragma unroll
        for (int o = 0; o < NO; ++o) {
            const float* wo = wp + o * (DI * DE);
            const float bv = bp[o];
            float4 uji = make_float4(bv, bv, bv, bv);
#pragma unroll
            for (int d = 0; d < DI; ++d) {
                const float4 w4 = *(const float4*)(wo + d * DE);
                uji.x += ur[d] * w4.x; uji.y += ur[d] * w4.y;
                uji.z += ur[d] * w4.z; uji.w += ur[d] * w4.w;
            }
            const float c = cp[o];
            acc[o].x += c * uji.x; acc[o].y += c * uji.y;
            acc[o].z += c * uji.z; acc[o].w += c * uji.w;
        }
    }

    // reduce the 8-way n split (lane-xor 4, 8, 16; bb bit is lane bit 5, untouched)
#pragma unroll
    for (int o = 0; o < NO; ++o) {
#pragma unroll
        for (int msk = 4; msk <= 16; msk <<= 1) {
            acc[o].x += __shfl_xor(acc[o].x, msk);
            acc[o].y += __shfl_xor(acc[o].y, msk);
            acc[o].z += __shfl_xor(acc[o].z, msk);
            acc[o].w += __shfl_xor(acc[o].w, msk);
        }
    }
    if (npar == 0) {
        float* sp = s_part + ((size_t)blockIdx.x * B + b) * (NO * DE) + e4 * 4;
#pragma unroll
        for (int o = 0; o < NO; ++o) *(float4*)(sp + o * DE) = acc[o];
    }
}

// ---------------------------------------------------------------------------
// Squash: s = sum_nt s_part; v = ||s||/(1+||s||^2) * s; also sv[b,o] = sum_e v.
// One thread per (b,o,e); 16-lane shuffle groups share one (b,o).
// ---------------------------------------------------------------------------
__global__ __launch_bounds__(256)
void squash_kernel(const float* __restrict__ s_part,
                   float* __restrict__ v,
                   float* __restrict__ sv,
                   float* __restrict__ out) {
    const int g = blockIdx.x * 256 + threadIdx.x;  // < B*NO*DE = 40960
    float s = 0.f;
#pragma unroll
    for (int t = 0; t < NT; ++t) s += s_part[(size_t)t * (B * NO * DE) + g];

    float nsq  = s * s;
    float ssum = s;
#pragma unroll
    for (int msk = 1; msk <= 8; msk <<= 1) {
        nsq  += __shfl_xor(nsq,  msk);
        ssum += __shfl_xor(ssum, msk);
    }
    const float nrm   = sqrtf(nsq);
    const float scale = nrm / (1.f + nsq);
    const float val   = s * scale;
    v[g]   = val;
    out[g] = val;
    if ((g & 15) == 0) sv[g >> 4] = ssum * scale;  // g>>4 == b*NO+o
}

// ---------------------------------------------------------------------------
// Phase 2: logits[b,n,o] += sum_e u_ji[b,n,o,e]*v[b,o,e]
//        = sum_{d,e} u[b,n,d]*w[n,o,d,e]*v[b,o,e] + bias[n,o]*sv[b,o]
// Same thread map as phase1; e4 quads reduce via shfl_xor(1,2).
// ---------------------------------------------------------------------------
__global__ __launch_bounds__(THREADS)
void phase2_kernel(const float* __restrict__ u,
                   const float* __restrict__ w,
                   const float* __restrict__ bias,
                   const float* __restrict__ v,
                   const float* __restrict__ sv,
                   float* __restrict__ logits) {
    __shared__ __align__(16) float v_s[BPB * NO * DE];  // 10,240 B
    __shared__ float sv_s[BPB * NO];                    // 640 B
    const int n0 = blockIdx.x * NPB;
    const int b0 = blockIdx.y * BPB;
    const int tid = threadIdx.x;

    for (int i = tid; i < BPB * NO * DE; i += THREADS)
        v_s[i] = v[(size_t)b0 * NO * DE + i];
    for (int i = tid; i < BPB * NO; i += THREADS)
        sv_s[i] = sv[b0 * NO + i];
    __syncthreads();

    const int bb   = tid >> 5;
    const int sub  = tid & 31;
    const int npar = sub >> 2;
    const int e4   = sub & 3;
    const int b    = b0 + bb;

    for (int nl = npar; nl < NPB; nl += 8) {
        const int n = n0 + nl;
        const float* up = u + ((size_t)b * N + n) * DI;
        const float4 u0 = *(const float4*)up;
        const float4 u1 = *(const float4*)(up + 4);
        const float ur[DI] = {u0.x, u0.y, u0.z, u0.w, u1.x, u1.y, u1.z, u1.w};
        const float* wp = w + (size_t)n * (NO * DI * DE) + e4 * 4;
        const float* bp = bias + n * NO;
        float* lp = logits + ((size_t)b * N + n) * NO;
#pragma unroll
        for (int o = 0; o < NO; ++o) {
            const float* wo = wp + o * (DI * DE);
            float4 uw = make_float4(0.f, 0.f, 0.f, 0.f);
#pragma unroll
            for (int d = 0; d < DI; ++d) {
                const float4 w4 = *(const float4*)(wo + d * DE);
                uw.x += ur[d] * w4.x; uw.y += ur[d] * w4.y;
                uw.z += ur[d] * w4.z; uw.w += ur[d] * w4.w;
            }
            const float4 v4 = *(const float4*)&v_s[(bb * NO + o) * DE + e4 * 4];
            float p = uw.x * v4.x + uw.y * v4.y + uw.z * v4.z + uw.w * v4.w;
            p += __shfl_xor(p, 1);
            p += __shfl_xor(p, 2);
            if (e4 == 0)
                lp[o] += p + bp[o] * sv_s[bb * NO + o];
        }
    }
}

extern "C" void kernel_launch(void* const* d_in, const int* in_sizes, int n_in,
                              void* d_out, int out_size, void* d_ws, size_t ws_size,
                              hipStream_t stream) {
    const float* u    = (const float*)d_in[0];
    const float* w    = (const float*)d_in[1];   // (1,N,NO,DI,DE) -> (N,NO,DI,DE)
    const float* bias = (const float*)d_in[2];   // (N,NO,1)
    // d_in[3] is r; fixed at 3 by the problem setup.

    float* ws     = (float*)d_ws;
    float* logits = ws + LOGITS_OFF;
    float* s_part = ws + SPART_OFF;
    float* vbuf   = ws + V_OFF;
    float* svbuf  = ws + SV_OFF;
    float* out    = (float*)d_out;

    hipMemsetAsync(logits, 0, (size_t)LOGITS_SZ * sizeof(float), stream);

    const dim3 grid(NT, BT), blk(THREADS);
    for (int it = 0; it < 3; ++it) {
        phase1_kernel<<<grid, blk, 0, stream>>>(u, w, bias, logits, s_part);
        squash_kernel<<<(B * NO * DE) / 256, 256, 0, stream>>>(s_part, vbuf, svbuf, out);
        if (it < 2)
            phase2_kernel<<<grid, blk, 0, stream>>>(u, w, bias, vbuf, svbuf, logits);
    }
}

// Round 2
// 306.271 us; speedup vs baseline: 1.5785x; 1.5785x over previous
//
#include <hip/hip_runtime.h>

// Capsule dynamic routing — fused recompute, broadcast-friendly lane layout.
// u_i:(B,N,DI) f32, w:(1,N,NO,DI,DE) f32, bias:(N,NO,1) f32, r=3.
// Per iteration r: per (b,n): recompute u_ji (10x16); if r>0: logits += u_ji.v,
// softmax; s += c*u_ji (atomic into (o,e,b) buffer); then squash.
// Layouts: u_t (N,DI,B), logits (N,NO,B), s/v_t (NO,DE,B) -> lane-coalesced in b.

#define B    256
#define N    1152
#define NO   10
#define DI   8
#define DE   16
#define NTILE  12
#define NTILES 96
#define BTILE  32
#define BTILES 8

// ws layout (floats)
#define UT_OFF 0
#define UT_SZ  (N * DI * B)      // 2,359,296
#define LG_OFF (UT_OFF + UT_SZ)
#define LG_SZ  (N * NO * B)      // 2,949,120
#define S_OFF  (LG_OFF + LG_SZ)
#define S_SZ   (NO * DE * B)     // 40,960
#define VT_OFF (S_OFF + S_SZ)
#define VT_SZ  (NO * DE * B)     // 40,960

// ---------------------------------------------------------------------------
// Transpose u (B, N*DI) -> u_t (N*DI, B). 64x64 LDS tiles.
// ---------------------------------------------------------------------------
__global__ __launch_bounds__(256)
void transpose_u(const float* __restrict__ u, float* __restrict__ u_t) {
    __shared__ float t[64][65];
    const int k0 = blockIdx.x * 64;   // k = n*DI + d, 144 tiles
    const int b0 = blockIdx.y * 64;   // 4 tiles
    const int kx = threadIdx.x & 63;
    const int q  = threadIdx.x >> 6;
#pragma unroll
    for (int i = 0; i < 16; ++i) {
        const int br = q * 16 + i;
        t[br][kx] = u[(size_t)(b0 + br) * (N * DI) + k0 + kx];
    }
    __syncthreads();
#pragma unroll
    for (int i = 0; i < 16; ++i) {
        const int kr = q * 16 + i;
        u_t[(size_t)(k0 + kr) * B + b0 + kx] = t[kx][kr];
    }
}

// ---------------------------------------------------------------------------
// Fused routing phase. Lane bits: e4 = lane&3, oh = (lane>>2)&1, bb = rest.
// Each thread owns (b, o-half[5], e-quad[4]); loops NTILE n's.
// ---------------------------------------------------------------------------
__global__ __launch_bounds__(256)
void routing_kernel(const float* __restrict__ u_t,
                    const float* __restrict__ w,
                    const float* __restrict__ bias,
                    const float* __restrict__ v_t,
                    float* __restrict__ logits,
                    float* __restrict__ s,
                    const int has_v, const int load_logits) {
    const int tid   = threadIdx.x;
    const int lane  = tid & 63;
    const int e4    = lane & 3;             // e-quad: e = e4*4+j
    const int oh    = (lane >> 2) & 1;      // o-half: o = oh*5+ok
    const int bb    = (tid >> 6) * 8 + ((tid >> 3) & 7);
    const int b     = blockIdx.y * BTILE + bb;
    const int n0    = blockIdx.x * NTILE;
    const int obase = oh * 5;

    // v fragment for the dot (reused across all n) — 20 scalars
    float4 vv[5];
#pragma unroll
    for (int ok = 0; ok < 5; ++ok) vv[ok] = make_float4(0.f, 0.f, 0.f, 0.f);
    if (has_v) {
#pragma unroll
        for (int ok = 0; ok < 5; ++ok) {
            const float* vp = v_t + (size_t)((obase + ok) * DE + e4 * 4) * B + b;
            vv[ok].x = vp[0 * B]; vv[ok].y = vp[1 * B];
            vv[ok].z = vp[2 * B]; vv[ok].w = vp[3 * B];
        }
    }

    float4 acc[5];
#pragma unroll
    for (int ok = 0; ok < 5; ++ok) acc[ok] = make_float4(0.f, 0.f, 0.f, 0.f);

    for (int i = 0; i < NTILE; ++i) {
        const int n = n0 + i;
        // u row (broadcast across oh/e4 lanes, contiguous across bb lanes)
        float ur[DI];
#pragma unroll
        for (int d = 0; d < DI; ++d) ur[d] = u_t[(size_t)(n * DI + d) * B + b];

        // recompute u_ji for this thread's (o-half, e-quad)
        const float* wp = w + ((size_t)n * NO + obase) * (DI * DE) + e4 * 4;
        float4 uji[5];
#pragma unroll
        for (int ok = 0; ok < 5; ++ok) {
            const float bv = bias[n * NO + obase + ok];
            float4 a = make_float4(bv, bv, bv, bv);
            const float* wo = wp + ok * (DI * DE);
#pragma unroll
            for (int d = 0; d < DI; ++d) {
                const float4 w4 = *(const float4*)(wo + d * DE);
                a.x += ur[d] * w4.x; a.y += ur[d] * w4.y;
                a.z += ur[d] * w4.z; a.w += ur[d] * w4.w;
            }
            uji[ok] = a;
        }

        float c[5];
        if (has_v) {
            float lg[5];
#pragma unroll
            for (int ok = 0; ok < 5; ++ok) {
                float dt = uji[ok].x * vv[ok].x + uji[ok].y * vv[ok].y
                         + uji[ok].z * vv[ok].z + uji[ok].w * vv[ok].w;
                dt += __shfl_xor(dt, 1);        // butterfly over e4 bits
                dt += __shfl_xor(dt, 2);        // -> full sum over e=0..15
                const size_t li = (size_t)(n * NO + obase + ok) * B + b;
                const float old = load_logits ? logits[li] : 0.f;
                lg[ok] = old + dt;
            }
            if (e4 == 0) {
#pragma unroll
                for (int ok = 0; ok < 5; ++ok)
                    logits[(size_t)(n * NO + obase + ok) * B + b] = lg[ok];
            }
            // softmax over all 10 o (exchange with other o-half: lane bit 2)
            float m = lg[0];
#pragma unroll
            for (int ok = 1; ok < 5; ++ok) m = fmaxf(m, lg[ok]);
            m = fmaxf(m, __shfl_xor(m, 4));
            float p[5], sl = 0.f;
#pragma unroll
            for (int ok = 0; ok < 5; ++ok) { p[ok] = __expf(lg[ok] - m); sl += p[ok]; }
            sl += __shfl_xor(sl, 4);
            const float inv = 1.f / sl;
#pragma unroll
            for (int ok = 0; ok < 5; ++ok) c[ok] = p[ok] * inv;
        } else {
#pragma unroll
            for (int ok = 0; ok < 5; ++ok) c[ok] = 0.1f;   // softmax of zeros
        }

#pragma unroll
        for (int ok = 0; ok < 5; ++ok) {
            acc[ok].x += c[ok] * uji[ok].x; acc[ok].y += c[ok] * uji[ok].y;
            acc[ok].z += c[ok] * uji[ok].z; acc[ok].w += c[ok] * uji[ok].w;
        }
    }

    // s (o,e,b) += acc ; <=96-way contention per address, spread in time
#pragma unroll
    for (int ok = 0; ok < 5; ++ok) {
        float* sp = s + (size_t)((obase + ok) * DE + e4 * 4) * B + b;
        atomicAdd(sp + 0 * B, acc[ok].x);
        atomicAdd(sp + 1 * B, acc[ok].y);
        atomicAdd(sp + 2 * B, acc[ok].z);
        atomicAdd(sp + 3 * B, acc[ok].w);
    }
}

// ---------------------------------------------------------------------------
// Squash: v = ||s||/(1+||s||^2) * s. Lane bits 0-3 = e -> in-wave norm reduce.
// Writes v_t (NO,DE,B) for next routing pass and out (B,NO,DE).
// ---------------------------------------------------------------------------
__global__ __launch_bounds__(256)
void squash_kernel(const float* __restrict__ s,
                   float* __restrict__ v_t,
                   float* __restrict__ out) {
    const int g = blockIdx.x * 256 + threadIdx.x;   // < NO*DE*B = 40960
    const int e = g & 15;
    const int b = (g >> 4) & 255;
    const int o = g >> 12;
    const float sv = s[(size_t)(o * DE + e) * B + b];
    float nsq = sv * sv;
#pragma unroll
    for (int msk = 1; msk <= 8; msk <<= 1) nsq += __shfl_xor(nsq, msk);
    const float nrm   = sqrtf(nsq);
    const float scale = nrm / (1.f + nsq);
    const float val   = sv * scale;
    v_t[(size_t)(o * DE + e) * B + b] = val;
    out[(size_t)(b * NO + o) * DE + e] = val;
}

extern "C" void kernel_launch(void* const* d_in, const int* in_sizes, int n_in,
                              void* d_out, int out_size, void* d_ws, size_t ws_size,
                              hipStream_t stream) {
    const float* u    = (const float*)d_in[0];
    const float* w    = (const float*)d_in[1];   // (N,NO,DI,DE)
    const float* bias = (const float*)d_in[2];   // (N,NO)
    // d_in[3] = r, static 3

    float* wsf    = (float*)d_ws;
    float* u_t    = wsf + UT_OFF;
    float* logits = wsf + LG_OFF;
    float* s      = wsf + S_OFF;
    float* v_t    = wsf + VT_OFF;
    float* out    = (float*)d_out;

    transpose_u<<<dim3((N * DI) / 64, B / 64), 256, 0, stream>>>(u, u_t);

    for (int it = 0; it < 3; ++it) {
        hipMemsetAsync(s, 0, (size_t)S_SZ * sizeof(float), stream);
        routing_kernel<<<dim3(NTILES, BTILES), 256, 0, stream>>>(
            u_t, w, bias, v_t, logits, s, it > 0, it > 1);
        squash_kernel<<<(NO * DE * B) / 256, 256, 0, stream>>>(s, v_t, out);
    }
}